// Round 6
// baseline (261.773 us; speedup 1.0000x reference)
//
#include <hip/hip_runtime.h>

#define DEV_INLINE __device__ __forceinline__

constexpr int BATCH = 2;
constexpr int HH = 96, WW = 96, CC = 96;
constexpr int DI = 192;              // d_inner == mamba d_model
constexpr int NS = 16;               // d_state
constexpr int LSEQ = HH * WW;        // 9216
constexpr int TT = BATCH * LSEQ;     // 18432 tokens
constexpr int CHUNK = 32;            // scan chunk length
constexpr int NCHUNK = LSEQ / CHUNK; // 288 chunks per batch
constexpr int QDN = DI * NS;         // 3072

typedef __attribute__((ext_vector_type(8))) short bf16x8;
typedef __attribute__((ext_vector_type(4))) float f32x4;

DEV_INLINE float silu_f(float x) { return x / (1.f + __expf(-x)); }
DEV_INLINE float softplus_f(float x) {
  return fmaxf(x, 0.f) + log1pf(__expf(-fabsf(x)));
}
DEV_INLINE ushort f2bf(float f) {
  union { float f; unsigned u; } c; c.f = f;
  unsigned u = c.u + 0x7FFF + ((c.u >> 16) & 1);   // RNE
  return (ushort)(u >> 16);
}
DEV_INLINE float bf2f(ushort u) {
  union { unsigned u; float f; } c; c.u = ((unsigned)u) << 16; return c.f;
}

// ---------------- weight cast + transpose to bf16 [N][K] ----------------
// t0: in_proj  W[96 x384] -> [384][96]
// t1: m_in     W[192x384] -> [384][192]
// t2: m_out    W[192x192] -> [192][192]
// t3: out_proj W[192x 96] -> [128][192] (rows 96..127 zero)
// t4: x_proj   W[192x 44] -> Wxt[48][192], rows: 0..15=B, 16..31=C, 32..43=dt, 44..47=0
// t5: dt_proj  W[12 x192] -> Wdtt[192][32] (cols 12..31 zero)
// t6: conv1d   w[192][3]  -> cwT[3][192] fp32
__global__ __launch_bounds__(256)
void castw_kernel(const float* __restrict__ w0, const float* __restrict__ w1,
                  const float* __restrict__ w2, const float* __restrict__ w3,
                  const float* __restrict__ wx, const float* __restrict__ wdt,
                  const float* __restrict__ wc1,
                  ushort* __restrict__ t0, ushort* __restrict__ t1,
                  ushort* __restrict__ t2, ushort* __restrict__ t3,
                  ushort* __restrict__ t4, ushort* __restrict__ t5,
                  float* __restrict__ cwT)
{
  int id = blockIdx.x * 256 + threadIdx.x;      // 187968 total
  if (id < 36864) {
    int k = id % 96, n = id / 96;
    t0[id] = f2bf(w0[k * 384 + n]);
  } else if (id < 110592) {
    int j = id - 36864; int k = j % 192, n = j / 192;
    t1[j] = f2bf(w1[k * 384 + n]);
  } else if (id < 147456) {
    int j = id - 110592; int k = j % 192, n = j / 192;
    t2[j] = f2bf(w2[k * 192 + n]);
  } else if (id < 172032) {
    int j = id - 147456; int k = j % 192, n = j / 192;
    t3[j] = (n < 96) ? f2bf(w3[k * 96 + n]) : (ushort)0;
  } else if (id < 181248) {
    int j = id - 172032; int k = j % 192, n = j / 192;    // Wxt[48][192]
    float v = 0.f;
    if (n < 16) v = wx[k * 44 + 12 + n];
    else if (n < 32) v = wx[k * 44 + 28 + (n - 16)];
    else if (n < 44) v = wx[k * 44 + (n - 32)];
    t4[j] = f2bf(v);
  } else if (id < 187392) {
    int j = id - 181248; int r = j % 32, d = j / 32;      // Wdtt[192][32]
    t5[j] = (r < 12) ? f2bf(wdt[r * 192 + d]) : (ushort)0;
  } else if (id < 187968) {
    int j = id - 187392; int k = j / 192, d = j % 192;    // cwT[3][192]
    cwT[j] = wc1[d * 3 + k];
  }
}

// ---------------- fused LayerNorm + in_proj MFMA GEMM ----------------
// Block: 128 tokens x 64 n-cols; LN computed inline (2 threads/row) into LDS bf16.
__global__ __launch_bounds__(256)
void ln_inproj_kernel(const float* __restrict__ x, const float* __restrict__ nw,
                      const float* __restrict__ nbias, const ushort* __restrict__ Wt0,
                      ushort* __restrict__ xz0)
{
  __shared__ ushort sA[128][104];   // stride 104: 2-way bank aliasing only (free)
  const int tid = threadIdx.x;
  const int m0 = blockIdx.x * 128;
  const int n0 = blockIdx.y * 64;
  {
    const int tok = tid >> 1, h = tid & 1;
    const float* xr = x + (size_t)(m0 + tok) * 96 + h * 48;
    float v[48];
    float s = 0.f, ss = 0.f;
#pragma unroll
    for (int i = 0; i < 12; ++i) {
      float4 t4 = *(const float4*)(xr + i * 4);
      v[i*4+0] = t4.x; v[i*4+1] = t4.y; v[i*4+2] = t4.z; v[i*4+3] = t4.w;
      s += (t4.x + t4.y) + (t4.z + t4.w);
      ss += (t4.x*t4.x + t4.y*t4.y) + (t4.z*t4.z + t4.w*t4.w);
    }
    s += __shfl_xor(s, 1);
    ss += __shfl_xor(ss, 1);
    float mean = s * (1.f/96.f);
    float var = ss * (1.f/96.f) - mean*mean;
    float rstd = rsqrtf(var + 1e-5f);
    const float* wr = nw + h*48;
    const float* br = nbias + h*48;
#pragma unroll
    for (int i = 0; i < 12; ++i) {
      float4 w4 = *(const float4*)(wr + i*4);
      float4 b4 = *(const float4*)(br + i*4);
      unsigned p0 = (unsigned)f2bf((v[i*4+0]-mean)*rstd*w4.x + b4.x)
                  | ((unsigned)f2bf((v[i*4+1]-mean)*rstd*w4.y + b4.y) << 16);
      unsigned p1 = (unsigned)f2bf((v[i*4+2]-mean)*rstd*w4.z + b4.z)
                  | ((unsigned)f2bf((v[i*4+3]-mean)*rstd*w4.w + b4.w) << 16);
      unsigned* dst = (unsigned*)&sA[tok][h*48 + i*4];
      dst[0] = p0; dst[1] = p1;
    }
  }
  __syncthreads();

  const int wid = tid >> 6, lane = tid & 63;
  const int wm = wid >> 1, wn = wid & 1;
  const int l16 = lane & 15, quad = lane >> 4;
  const f32x4 z4 = {0.f, 0.f, 0.f, 0.f};
  f32x4 acc[4][2];
#pragma unroll
  for (int i = 0; i < 4; ++i)
#pragma unroll
    for (int j = 0; j < 2; ++j) acc[i][j] = z4;

#pragma unroll
  for (int k0 = 0; k0 < 96; k0 += 32) {
    bf16x8 xf[4], wf[2];
#pragma unroll
    for (int i = 0; i < 4; ++i)
      xf[i] = *(const bf16x8*)&sA[wm*64 + i*16 + l16][k0 + quad*8];
#pragma unroll
    for (int j = 0; j < 2; ++j)
      wf[j] = *(const bf16x8*)(Wt0 + (size_t)(n0 + wn*32 + j*16 + l16) * 96 + k0 + quad*8);
#pragma unroll
    for (int i = 0; i < 4; ++i)
#pragma unroll
      for (int j = 0; j < 2; ++j)
        acc[i][j] = __builtin_amdgcn_mfma_f32_16x16x32_bf16(wf[j], xf[i], acc[i][j], 0, 0, 0);
  }
#pragma unroll
  for (int i = 0; i < 4; ++i) {
    const int token = m0 + wm*64 + i*16 + l16;
#pragma unroll
    for (int j = 0; j < 2; ++j) {
      const int nb = n0 + wn*32 + j*16 + quad*4;
      ushort4 o;
      o.x = f2bf(acc[i][j][0]); o.y = f2bf(acc[i][j][1]);
      o.z = f2bf(acc[i][j][2]); o.w = f2bf(acc[i][j][3]);
      *(ushort4*)(xz0 + (size_t)token * 384 + nb) = o;
    }
  }
}

// ---------------- bf16 MFMA GEMM (m_in_proj), swapped-operand ----------------
__global__ __launch_bounds__(256)
void mfma_gemm_kernel(const ushort* __restrict__ A, int lda,
                      const ushort* __restrict__ Bt, int ldb,
                      ushort* __restrict__ Cout, int ldc, int K)
{
  const int tid = threadIdx.x;
  const int wid = tid >> 6, lane = tid & 63;
  const int wm = wid >> 1, wn = wid & 1;
  const int m0 = blockIdx.x * 128 + wm * 64;
  const int n0 = blockIdx.y * 64 + wn * 32;
  const int l16 = lane & 15, quad = lane >> 4;

  f32x4 acc[4][2];
  const f32x4 z4 = {0.f, 0.f, 0.f, 0.f};
#pragma unroll
  for (int i = 0; i < 4; ++i)
#pragma unroll
    for (int j = 0; j < 2; ++j) acc[i][j] = z4;

  for (int k0 = 0; k0 < K; k0 += 32) {
    bf16x8 xf[4], wf[2];
#pragma unroll
    for (int i = 0; i < 4; ++i)
      xf[i] = *(const bf16x8*)(A + (size_t)(m0 + i * 16 + l16) * lda + k0 + quad * 8);
#pragma unroll
    for (int j = 0; j < 2; ++j)
      wf[j] = *(const bf16x8*)(Bt + (size_t)(n0 + j * 16 + l16) * ldb + k0 + quad * 8);
#pragma unroll
    for (int i = 0; i < 4; ++i)
#pragma unroll
      for (int j = 0; j < 2; ++j)
        acc[i][j] = __builtin_amdgcn_mfma_f32_16x16x32_bf16(wf[j], xf[i], acc[i][j], 0, 0, 0);
  }
#pragma unroll
  for (int i = 0; i < 4; ++i) {
    const int token = m0 + i * 16 + l16;
#pragma unroll
    for (int j = 0; j < 2; ++j) {
      const int nb = n0 + j * 16 + quad * 4;
      ushort4 o;
      o.x = f2bf(acc[i][j][0]); o.y = f2bf(acc[i][j][1]);
      o.z = f2bf(acc[i][j][2]); o.w = f2bf(acc[i][j][3]);
      *(ushort4*)(Cout + (size_t)token * ldc + nb) = o;
    }
  }
}

// ---------------- depthwise 3x3 conv + SiLU, bf16 in/out (channels-last) ----------------
__global__ __launch_bounds__(256)
void conv2d_silu_kernel(const ushort* __restrict__ xz0, const float* __restrict__ w,
                        ushort* __restrict__ xc)
{
  __shared__ float ws[DI * 9];
  for (int i = threadIdx.x; i < DI * 9; i += 256) ws[i] = w[i];
  __syncthreads();
  int id = blockIdx.x * 256 + threadIdx.x;     // TT*48
  int dq = id % 48;
  int p  = id / 48;
  int j = p % WW;
  int i = (p / WW) % HH;
  int b = p / (WW * HH);
  int d = dq * 4;
  float a0 = 0.f, a1 = 0.f, a2 = 0.f, a3 = 0.f;
#pragma unroll
  for (int ki = 0; ki < 3; ++ki) {
    int ii = i + ki - 1;
    if (ii < 0 || ii >= HH) continue;
#pragma unroll
    for (int kj = 0; kj < 3; ++kj) {
      int jj = j + kj - 1;
      if (jj < 0 || jj >= WW) continue;
      const ushort4 v = *(const ushort4*)(xz0 + ((size_t)((b * HH + ii) * WW + jj)) * 384 + d);
      int wk = ki * 3 + kj;
      a0 = fmaf(bf2f(v.x), ws[(d + 0) * 9 + wk], a0);
      a1 = fmaf(bf2f(v.y), ws[(d + 1) * 9 + wk], a1);
      a2 = fmaf(bf2f(v.z), ws[(d + 2) * 9 + wk], a2);
      a3 = fmaf(bf2f(v.w), ws[(d + 3) * 9 + wk], a3);
    }
  }
  ushort4 o;
  o.x = f2bf(silu_f(a0)); o.y = f2bf(silu_f(a1));
  o.z = f2bf(silu_f(a2)); o.w = f2bf(silu_f(a3));
  *(ushort4*)(xc + (size_t)p * DI + d) = o;
}

// ---------------- fused mamba prep: conv1d+SiLU inline -> x_proj MFMA -> dt shfl -> dt_proj MFMA
// One wave per 16-token strip. Grid = TT/16 = 1152 blocks of 64 threads.
__global__ __launch_bounds__(64)
void mprep_kernel(const ushort* __restrict__ xz1, const float* __restrict__ cwT,
                  const float* __restrict__ cb, const ushort* __restrict__ Wxt,
                  const ushort* __restrict__ Wdtt, const float* __restrict__ bdt,
                  ushort* __restrict__ xmb, float* __restrict__ xdbl_bc,
                  float* __restrict__ dlt)
{
  const int lane = threadIdx.x;
  const int l16 = lane & 15, quad = lane >> 4;
  const int t = blockIdx.x * 16 + l16;                 // this lane's token
  const int l = (t >= LSEQ) ? t - LSEQ : t;            // position within sequence
  const f32x4 z4 = {0.f, 0.f, 0.f, 0.f};
  f32x4 accB = z4, accC = z4, accD = z4;

#pragma unroll
  for (int k0 = 0; k0 < 192; k0 += 32) {
    const int c = k0 + quad * 8;
    float4 b0 = *(const float4*)(cb + c);
    float4 b1 = *(const float4*)(cb + c + 4);
    float u[8] = {b0.x, b0.y, b0.z, b0.w, b1.x, b1.y, b1.z, b1.w};
#pragma unroll
    for (int k = 0; k < 3; ++k) {
      if (l + k - 2 < 0) continue;
      bf16x8 xv = *(const bf16x8*)(xz1 + (size_t)(t + k - 2) * 384 + c);
      float4 w0 = *(const float4*)(cwT + k * 192 + c);
      float4 w1 = *(const float4*)(cwT + k * 192 + c + 4);
      u[0] = fmaf(bf2f((ushort)xv[0]), w0.x, u[0]);
      u[1] = fmaf(bf2f((ushort)xv[1]), w0.y, u[1]);
      u[2] = fmaf(bf2f((ushort)xv[2]), w0.z, u[2]);
      u[3] = fmaf(bf2f((ushort)xv[3]), w0.w, u[3]);
      u[4] = fmaf(bf2f((ushort)xv[4]), w1.x, u[4]);
      u[5] = fmaf(bf2f((ushort)xv[5]), w1.y, u[5]);
      u[6] = fmaf(bf2f((ushort)xv[6]), w1.z, u[6]);
      u[7] = fmaf(bf2f((ushort)xv[7]), w1.w, u[7]);
    }
    bf16x8 uf;
#pragma unroll
    for (int jj = 0; jj < 8; ++jj) uf[jj] = (short)f2bf(silu_f(u[jj]));
    *(uint4*)(xmb + (size_t)t * DI + c) = *(uint4*)&uf;   // u for the scan

    bf16x8 wB = *(const bf16x8*)(Wxt + (size_t)(l16) * 192 + c);
    bf16x8 wC = *(const bf16x8*)(Wxt + (size_t)(16 + l16) * 192 + c);
    bf16x8 wD = *(const bf16x8*)(Wxt + (size_t)(32 + l16) * 192 + c);
    accB = __builtin_amdgcn_mfma_f32_16x16x32_bf16(wB, uf, accB, 0, 0, 0);
    accC = __builtin_amdgcn_mfma_f32_16x16x32_bf16(wC, uf, accC, 0, 0, 0);
    accD = __builtin_amdgcn_mfma_f32_16x16x32_bf16(wD, uf, accD, 0, 0, 0);
  }
  // store B, C (fp32)
  *(float4*)(xdbl_bc + (size_t)t * 32 + quad * 4) =
      make_float4(accB[0], accB[1], accB[2], accB[3]);
  *(float4*)(xdbl_bc + (size_t)t * 32 + 16 + quad * 4) =
      make_float4(accC[0], accC[1], accC[2], accC[3]);

  // redistribute dt from D-layout (lane quad*16+tok holds dt[tok][quad*4+r])
  // to A/B-frag layout (lane quad*16+tok needs dt[tok][quad*8+j])
  bf16x8 dtf;
#pragma unroll
  for (int j = 0; j < 8; ++j) {
    int n = quad * 8 + j;                     // dt index k
    int src = ((n >> 2) & 3) * 16 + l16;
    float tv = __shfl(accD[j & 3], src);
    dtf[j] = (short)((n < 16) ? f2bf(tv) : (ushort)0);
  }
  // dt_proj: delta[t][0..191] = softplus(dt @ Wdt + b)
  f32x4 acc2[12];
#pragma unroll
  for (int jj = 0; jj < 12; ++jj) {
    bf16x8 wf = *(const bf16x8*)(Wdtt + (size_t)(jj * 16 + l16) * 32 + quad * 8);
    acc2[jj] = __builtin_amdgcn_mfma_f32_16x16x32_bf16(wf, dtf, z4, 0, 0, 0);
  }
#pragma unroll
  for (int jj = 0; jj < 12; ++jj) {
    const int nb = jj * 16 + quad * 4;
    float4 b4 = *(const float4*)(bdt + nb);
    float4 dv;
    dv.x = softplus_f(acc2[jj][0] + b4.x);
    dv.y = softplus_f(acc2[jj][1] + b4.y);
    dv.z = softplus_f(acc2[jj][2] + b4.z);
    dv.w = softplus_f(acc2[jj][3] + b4.w);
    *(float4*)(dlt + (size_t)t * DI + nb) = dv;
  }
}

// ---------------- selective scan: thread = (b, chunk, d), 16 n-states in regs ----------------
__global__ __launch_bounds__(192)
void scan1_kernel(const float* __restrict__ dlt, const ushort* __restrict__ xmb,
                  const float* __restrict__ xdbl_bc, const float* __restrict__ Alog,
                  float* __restrict__ P, float* __restrict__ E)
{
  const int d = threadIdx.x;               // 0..191
  const int g = blockIdx.x % NCHUNK;
  const int b = blockIdx.x / NCHUNK;
  const int t0 = b * LSEQ + g * CHUNK;
  float Av[16];
#pragma unroll
  for (int j = 0; j < 16; ++j) Av[j] = -__expf(Alog[d * 16 + j]);
  float e[16];
#pragma unroll
  for (int j = 0; j < 16; ++j) e[j] = 0.f;
  float sdl = 0.f;
#pragma unroll 2
  for (int l = 0; l < CHUNK; ++l) {
    const int t = t0 + l;
    float dl = dlt[(size_t)t * DI + d];
    float u  = bf2f(xmb[(size_t)t * DI + d]);
    const float4 B0 = *(const float4*)(xdbl_bc + (size_t)t * 32 + 0);
    const float4 B1 = *(const float4*)(xdbl_bc + (size_t)t * 32 + 4);
    const float4 B2 = *(const float4*)(xdbl_bc + (size_t)t * 32 + 8);
    const float4 B3 = *(const float4*)(xdbl_bc + (size_t)t * 32 + 12);
    const float Bv[16] = {B0.x, B0.y, B0.z, B0.w, B1.x, B1.y, B1.z, B1.w,
                          B2.x, B2.y, B2.z, B2.w, B3.x, B3.y, B3.z, B3.w};
    float du = dl * u;
    sdl += dl;
#pragma unroll
    for (int j = 0; j < 16; ++j) {
      float a = __expf(dl * Av[j]);
      e[j] = fmaf(a, e[j], du * Bv[j]);
    }
  }
  size_t base = ((size_t)(b * NCHUNK + g)) * QDN + d * 16;
#pragma unroll
  for (int j = 0; j < 16; ++j) {
    P[base + j] = __expf(Av[j] * sdl);
    E[base + j] = e[j];
  }
}

// single-kernel mid-level scan: serial over all 288 chunks, writes per-chunk inbound state
__global__ __launch_bounds__(256)
void scan2_kernel(const float* __restrict__ P, const float* __restrict__ E,
                  float* __restrict__ Hin)
{
  int id = blockIdx.x * 256 + threadIdx.x;   // BATCH*QDN = 6144
  int q = id % QDN;
  int b = id / QDN;
  float h = 0.f;
#pragma unroll 8
  for (int g = 0; g < NCHUNK; ++g) {
    size_t idx = ((size_t)(b * NCHUNK + g)) * QDN + q;
    Hin[idx] = h;
    h = fmaf(P[idx], h, E[idx]);
  }
}

// phase3: replay chunk, y = (sum_n h*C + u*D) * silu(z) -> bf16
__global__ __launch_bounds__(192)
void scan3_kernel(const float* __restrict__ dlt, const ushort* __restrict__ xmb,
                  const float* __restrict__ xdbl_bc, const float* __restrict__ Alog,
                  const float* __restrict__ Dv, const ushort* __restrict__ xz1,
                  const float* __restrict__ Hin, ushort* __restrict__ yout)
{
  const int d = threadIdx.x;
  const int g = blockIdx.x % NCHUNK;
  const int b = blockIdx.x / NCHUNK;
  const int t0 = b * LSEQ + g * CHUNK;
  float Av[16];
#pragma unroll
  for (int j = 0; j < 16; ++j) Av[j] = -__expf(Alog[d * 16 + j]);
  const float Dd = Dv[d];
  float h[16];
  {
    size_t hb = ((size_t)(b * NCHUNK + g)) * QDN + d * 16;
#pragma unroll
    for (int j = 0; j < 16; ++j) h[j] = Hin[hb + j];
  }
#pragma unroll 2
  for (int l = 0; l < CHUNK; ++l) {
    const int t = t0 + l;
    float dl = dlt[(size_t)t * DI + d];
    float u  = bf2f(xmb[(size_t)t * DI + d]);
    const float4 B0 = *(const float4*)(xdbl_bc + (size_t)t * 32 + 0);
    const float4 B1 = *(const float4*)(xdbl_bc + (size_t)t * 32 + 4);
    const float4 B2 = *(const float4*)(xdbl_bc + (size_t)t * 32 + 8);
    const float4 B3 = *(const float4*)(xdbl_bc + (size_t)t * 32 + 12);
    const float4 C0 = *(const float4*)(xdbl_bc + (size_t)t * 32 + 16);
    const float4 C1 = *(const float4*)(xdbl_bc + (size_t)t * 32 + 20);
    const float4 C2 = *(const float4*)(xdbl_bc + (size_t)t * 32 + 24);
    const float4 C3 = *(const float4*)(xdbl_bc + (size_t)t * 32 + 28);
    const float Bv[16] = {B0.x, B0.y, B0.z, B0.w, B1.x, B1.y, B1.z, B1.w,
                          B2.x, B2.y, B2.z, B2.w, B3.x, B3.y, B3.z, B3.w};
    const float Cv[16] = {C0.x, C0.y, C0.z, C0.w, C1.x, C1.y, C1.z, C1.w,
                          C2.x, C2.y, C2.z, C2.w, C3.x, C3.y, C3.z, C3.w};
    float du = dl * u;
    float y0 = 0.f, y1 = 0.f, y2 = 0.f, y3 = 0.f;
#pragma unroll
    for (int j = 0; j < 16; ++j) {
      float a = __expf(dl * Av[j]);
      h[j] = fmaf(a, h[j], du * Bv[j]);
      if ((j & 3) == 0) y0 = fmaf(h[j], Cv[j], y0);
      else if ((j & 3) == 1) y1 = fmaf(h[j], Cv[j], y1);
      else if ((j & 3) == 2) y2 = fmaf(h[j], Cv[j], y2);
      else y3 = fmaf(h[j], Cv[j], y3);
    }
    float y = (y0 + y1) + (y2 + y3) + u * Dd;
    float z = bf2f(xz1[(size_t)t * 384 + 192 + d]);
    yout[(size_t)t * DI + d] = f2bf(y * silu_f(z));
  }
}

// ---------------- fused m_out_proj (silu gate) + out_proj (+residual) ----------------
// Block: 32 tokens, 256 threads (4 waves as 2x2). GEMM1 N=192 -> LDS bf16 -> GEMM2 N=96.
__global__ __launch_bounds__(256)
void outproj_kernel(const ushort* __restrict__ yfin, const ushort* __restrict__ Wt2,
                    const ushort* __restrict__ xz0, const ushort* __restrict__ Wt3,
                    const float* __restrict__ x, float* __restrict__ out)
{
  __shared__ ushort yg_s[32][200];   // stride 200: 2-way bank aliasing only
  const int tid = threadIdx.x;
  const int wid = tid >> 6, lane = tid & 63;
  const int wm = wid >> 1, wn = wid & 1;
  const int l16 = lane & 15, quad = lane >> 4;
  const int m0 = blockIdx.x * 32;
  const f32x4 z4 = {0.f, 0.f, 0.f, 0.f};

  // GEMM1: yg[32][192] = yfin @ Wt2^T, wave tile 16 tok x 96 n
  f32x4 acc[6];
#pragma unroll
  for (int j = 0; j < 6; ++j) acc[j] = z4;
  const int mt = m0 + wm * 16 + l16;
#pragma unroll
  for (int k0 = 0; k0 < 192; k0 += 32) {
    bf16x8 af = *(const bf16x8*)(yfin + (size_t)mt * 192 + k0 + quad * 8);
#pragma unroll
    for (int nj = 0; nj < 6; ++nj) {
      bf16x8 wf = *(const bf16x8*)(Wt2 + (size_t)(wn * 96 + nj * 16 + l16) * 192 + k0 + quad * 8);
      acc[nj] = __builtin_amdgcn_mfma_f32_16x16x32_bf16(wf, af, acc[nj], 0, 0, 0);
    }
  }
#pragma unroll
  for (int nj = 0; nj < 6; ++nj) {
    const int tok = wm * 16 + l16;           // token col = l16
    const int nb = wn * 96 + nj * 16 + quad * 4;
    const ushort4 g4 = *(const ushort4*)(xz0 + (size_t)(m0 + tok) * 384 + 192 + nb);
    float v0 = acc[nj][0] * silu_f(bf2f(g4.x));
    float v1 = acc[nj][1] * silu_f(bf2f(g4.y));
    float v2 = acc[nj][2] * silu_f(bf2f(g4.z));
    float v3 = acc[nj][3] * silu_f(bf2f(g4.w));
    unsigned p0 = (unsigned)f2bf(v0) | ((unsigned)f2bf(v1) << 16);
    unsigned p1 = (unsigned)f2bf(v2) | ((unsigned)f2bf(v3) << 16);
    unsigned* dst = (unsigned*)&yg_s[tok][nb];
    dst[0] = p0; dst[1] = p1;
  }
  __syncthreads();

  // GEMM2: out[32][96] = yg_s @ Wt3^T + x, wave tile 16 tok x 48 n
  f32x4 acc2[3];
#pragma unroll
  for (int j = 0; j < 3; ++j) acc2[j] = z4;
#pragma unroll
  for (int k0 = 0; k0 < 192; k0 += 32) {
    bf16x8 af = *(const bf16x8*)&yg_s[wm * 16 + l16][k0 + quad * 8];
#pragma unroll
    for (int nj = 0; nj < 3; ++nj) {
      bf16x8 wf = *(const bf16x8*)(Wt3 + (size_t)(wn * 48 + nj * 16 + l16) * 192 + k0 + quad * 8);
      acc2[nj] = __builtin_amdgcn_mfma_f32_16x16x32_bf16(wf, af, acc2[nj], 0, 0, 0);
    }
  }
#pragma unroll
  for (int nj = 0; nj < 3; ++nj) {
    const int tok = wm * 16 + l16;
    const int nb = wn * 48 + nj * 16 + quad * 4;
    const float4 r4 = *(const float4*)(x + (size_t)(m0 + tok) * 96 + nb);
    *(float4*)(out + (size_t)(m0 + tok) * 96 + nb) =
        make_float4(acc2[nj][0] + r4.x, acc2[nj][1] + r4.y,
                    acc2[nj][2] + r4.z, acc2[nj][3] + r4.w);
  }
}

// ---------------- launch ----------------
extern "C" void kernel_launch(void* const* d_in, const int* in_sizes, int n_in,
                              void* d_out, int out_size, void* d_ws, size_t ws_size,
                              hipStream_t stream)
{
  const float* x         = (const float*)d_in[0];
  const float* norm_w    = (const float*)d_in[1];
  const float* norm_b    = (const float*)d_in[2];
  const float* in_proj_w = (const float*)d_in[3];
  const float* conv2d_w  = (const float*)d_in[4];
  const float* m_in_proj = (const float*)d_in[5];
  const float* m_c1d_w   = (const float*)d_in[6];
  const float* m_c1d_b   = (const float*)d_in[7];
  const float* m_x_proj  = (const float*)d_in[8];
  const float* m_dt_w    = (const float*)d_in[9];
  const float* m_dt_b    = (const float*)d_in[10];
  const float* m_A_log   = (const float*)d_in[11];
  const float* m_D       = (const float*)d_in[12];
  const float* m_out_w   = (const float*)d_in[13];
  const float* out_w     = (const float*)d_in[14];
  float* out = (float*)d_out;

  char* wp = (char*)d_ws;
  auto alloc = [&](size_t bytes) {
    char* r = wp; wp += (bytes + 255) & ~(size_t)255; return r;
  };
  ushort* Wt0    = (ushort*)alloc(36864 * 2);      // [384][96]
  ushort* Wt1    = (ushort*)alloc(73728 * 2);      // [384][192]
  ushort* Wt2    = (ushort*)alloc(36864 * 2);      // [192][192]
  ushort* Wt3    = (ushort*)alloc(24576 * 2);      // [128][192]
  ushort* Wxt    = (ushort*)alloc(9216 * 2);       // [48][192]
  ushort* Wdtt   = (ushort*)alloc(6144 * 2);       // [192][32]
  float*  cwT    = (float*)alloc(576 * 4);         // [3][192]
  ushort* xz0    = (ushort*)alloc((size_t)TT * 384 * 2);   // x_in | gate (bf16)
  ushort* xc_bf  = (ushort*)alloc((size_t)TT * 192 * 2);
  ushort* xz1    = (ushort*)alloc((size_t)TT * 384 * 2);   // xm_pre | z (bf16)
  ushort* xmb_bf = (ushort*)alloc((size_t)TT * 192 * 2);
  float*  xdbl_bc= (float*)alloc((size_t)TT * 32 * 4);     // B | C (fp32)
  float*  dlt    = (float*)alloc((size_t)TT * 192 * 4);
  float*  Pb     = (float*)alloc((size_t)BATCH * NCHUNK * QDN * 4);
  float*  Eb     = (float*)alloc((size_t)BATCH * NCHUNK * QDN * 4);
  float*  Hin    = (float*)alloc((size_t)BATCH * NCHUNK * QDN * 4);
  ushort* yfin   = (ushort*)alloc((size_t)TT * 192 * 2);

  // 1. weight cast/transpose/permute
  castw_kernel<<<735, 256, 0, stream>>>(in_proj_w, m_in_proj, m_out_w, out_w,
                                        m_x_proj, m_dt_w, m_c1d_w,
                                        Wt0, Wt1, Wt2, Wt3, Wxt, Wdtt, cwT);
  // 2. LN + in_proj fused -> xz0 bf16
  ln_inproj_kernel<<<dim3(TT / 128, 6), 256, 0, stream>>>(x, norm_w, norm_b, Wt0, xz0);
  // 3. dw 3x3 conv + SiLU -> xc bf16
  conv2d_silu_kernel<<<TT * 48 / 256, 256, 0, stream>>>(xz0, conv2d_w, xc_bf);
  // 4. m_in_proj -> xz1 bf16
  mfma_gemm_kernel<<<dim3(TT / 128, 6), 256, 0, stream>>>(xc_bf, 192, Wt1, 192, xz1, 384, 192);
  // 5. fused conv1d + x_proj + dt_proj -> xmb_bf, xdbl_bc, dlt
  mprep_kernel<<<TT / 16, 64, 0, stream>>>(xz1, cwT, m_c1d_b, Wxt, Wdtt, m_dt_b,
                                           xmb_bf, xdbl_bc, dlt);
  // 6. chunked selective scan
  scan1_kernel<<<BATCH * NCHUNK, 192, 0, stream>>>(dlt, xmb_bf, xdbl_bc, m_A_log, Pb, Eb);
  scan2_kernel<<<BATCH * QDN / 256, 256, 0, stream>>>(Pb, Eb, Hin);
  scan3_kernel<<<BATCH * NCHUNK, 192, 0, stream>>>(dlt, xmb_bf, xdbl_bc, m_A_log, m_D, xz1, Hin, yfin);
  // 7. fused m_out_proj (gate) + out_proj (+residual) -> out
  outproj_kernel<<<TT / 32, 256, 0, stream>>>(yfin, Wt2, xz0, Wt3, x, out);
}